// Round 6
// baseline (187.631 us; speedup 1.0000x reference)
//
#include <hip/hip_runtime.h>
#include <hip/hip_bf16.h>

#define NSTEPS 20
#define BROWS  8192
#define LATENT 256
#define UDIM   16
#define HIDDEN 512
#define BM     32      // rows per block
#define XLD    296     // LDS row stride (bf16) for X=[z|u|pad], 288 cols used
#define HLD    520     // LDS row stride (bf16) for hidden, 512 cols used

// packed-weight footprint (shorts)
#define W1P_SHORTS (9 * 32 * 64 * 8)     // 147456
#define W2P_SHORTS (16 * 16 * 64 * 8)    // 131072

// Packed weights live in module-scope device memory: allocated at .so load
// time (no hipMalloc, no d_ws, no d_out aliasing, no cross-block sync needed).
// Re-packed from the immutable W1/W2 inputs on every kernel_launch call ->
// deterministic across graph replays.
__device__ __align__(16) short g_Wpack[W1P_SHORTS + W2P_SHORTS];

typedef __attribute__((ext_vector_type(8))) short bf16x8;
typedef __attribute__((ext_vector_type(4))) short bf16x4;
typedef __attribute__((ext_vector_type(4))) float f32x4;

__device__ __forceinline__ short f2bf(float x) {
    union { __hip_bfloat16 h; short s; } u;
    u.h = __float2bfloat16(x);
    return u.s;
}

__device__ __forceinline__ float tanh_fast(float x) {
    // tanh(x) = 1 - 2/(exp(2x)+1); robust at +-inf
    float e = __expf(2.0f * x);
    return 1.0f - 2.0f * __builtin_amdgcn_rcpf(e + 1.0f);
}

// Pack W1 (272x512, zero-padded K->288) and W2 (512x256) into per-fragment
// order: frag(kt,nt): lane l holds W[k = kt*32 + (l>>4)*8 + j][n = nt*16 + (l&15)],
// j=0..7, stored as 8 contiguous bf16 per lane (one 16B load per fragment).
__global__ void prep_weights(const float* __restrict__ W1, const float* __restrict__ W2) {
    short* W1p = g_Wpack;
    short* W2p = g_Wpack + W1P_SHORTS;
    int t = blockIdx.x * 256 + threadIdx.x;
    if (t < 9 * 32 * 64) {
        int l = t & 63, f = t >> 6;          // f: 0..287 = kt*32+nt
        int kt = f >> 5, nt = f & 31;
        int k0 = kt * 32 + ((l >> 4) << 3);
        int n = nt * 16 + (l & 15);
        bf16x8 o;
#pragma unroll
        for (int j = 0; j < 8; ++j) {
            int k = k0 + j;
            o[j] = (k < 272) ? f2bf(W1[k * 512 + n]) : (short)0;
        }
        *reinterpret_cast<bf16x8*>(W1p + t * 8) = o;
    } else if (t < 9 * 32 * 64 + 16 * 16 * 64) {
        int t2 = t - 9 * 32 * 64;
        int l = t2 & 63, f = t2 >> 6;        // f: 0..255 = kt*16+nt
        int kt = f >> 4, nt = f & 15;
        int k0 = kt * 32 + ((l >> 4) << 3);
        int n = nt * 16 + (l & 15);
        bf16x8 o;
#pragma unroll
        for (int j = 0; j < 8; ++j) o[j] = f2bf(W2[(k0 + j) * 256 + n]);
        *reinterpret_cast<bf16x8*>(W2p + t2 * 8) = o;
    }
}

// One block = 32 rows, 8 waves. Both GEMMs operand-swapped: D = W^T x X^T so
// the D fragment packs back into row-major [row][feature] LDS as contiguous
// b64 writes; activation B-fragments are contiguous b128 reads. z stays in
// f32 registers all 20 steps. Weights read from module-global g_Wpack.
__global__ __launch_bounds__(512, 2) void ode_kernel(
    const float* __restrict__ zt, const float* __restrict__ dtp,
    const float* __restrict__ ut, const float* __restrict__ b1,
    const float* __restrict__ b2, float* __restrict__ out) {
    __shared__ __align__(16) short X[BM * XLD];
    __shared__ __align__(16) short H[BM * HLD];

    const short* W1p = g_Wpack;
    const short* W2p = g_Wpack + W1P_SHORTS;

    const int tid = threadIdx.x;
    const int w = tid >> 6;          // wave 0..7
    const int l = tid & 63;
    const int l16 = l & 15;
    const int lg = l >> 4;           // 0..3
    const int row0 = blockIdx.x * BM;

    // biases for this wave's output tiles
    float b1v[4], b2v[2];
#pragma unroll
    for (int j = 0; j < 4; ++j) b1v[j] = b1[(w * 4 + j) * 16 + l16];
#pragma unroll
    for (int j = 0; j < 2; ++j) b2v[j] = b2[(w * 2 + j) * 16 + l16];

    // per-row step size h = dt/NSTEPS (one row per lane16 per mt)
    float hstep[2];
#pragma unroll
    for (int mt = 0; mt < 2; ++mt)
        hstep[mt] = dtp[row0 + mt * 16 + l16] * (1.0f / NSTEPS);

    // z registers: z[mt][j2][i] = z[row0+mt*16+l16][(w*2+j2)*16 + lg*4 + i]
    f32x4 z[2][2];
#pragma unroll
    for (int mt = 0; mt < 2; ++mt)
#pragma unroll
        for (int j2 = 0; j2 < 2; ++j2)
            z[mt][j2] = *reinterpret_cast<const f32x4*>(
                &zt[(row0 + mt * 16 + l16) * LATENT + (w * 2 + j2) * 16 + lg * 4]);

    // init: ut columns (256..271) + zero pad (272..287) of X
    {
        int r = tid >> 4, c = tid & 15;   // 512 threads = 32 rows x 16 cols
        X[r * XLD + 256 + c] = f2bf(ut[(row0 + r) * UDIM + c]);
        X[r * XLD + 272 + c] = 0;
    }
    // init: z columns of X (bf16)
#pragma unroll
    for (int mt = 0; mt < 2; ++mt)
#pragma unroll
        for (int j2 = 0; j2 < 2; ++j2) {
            bf16x4 p;
#pragma unroll
            for (int i = 0; i < 4; ++i) p[i] = f2bf(z[mt][j2][i]);
            *reinterpret_cast<bf16x4*>(&X[(mt * 16 + l16) * XLD + (w * 2 + j2) * 16 + lg * 4]) = p;
        }
    __syncthreads();

#pragma unroll 1
    for (int t = 0; t < NSTEPS; ++t) {
        // ---- GEMM1: hidden^T = W1^T (A) x X^T (B), K = 288
        f32x4 acc1[2][4];
#pragma unroll
        for (int mt = 0; mt < 2; ++mt)
#pragma unroll
            for (int j = 0; j < 4; ++j)
                acc1[mt][j] = (f32x4){b1v[j], b1v[j], b1v[j], b1v[j]};

#pragma unroll
        for (int kt = 0; kt < 9; ++kt) {
            bf16x8 xb0 = *reinterpret_cast<const bf16x8*>(&X[(0 * 16 + l16) * XLD + kt * 32 + lg * 8]);
            bf16x8 xb1 = *reinterpret_cast<const bf16x8*>(&X[(1 * 16 + l16) * XLD + kt * 32 + lg * 8]);
#pragma unroll
            for (int j = 0; j < 4; ++j) {
                int nt = w * 4 + j;
                bf16x8 af = *reinterpret_cast<const bf16x8*>(&W1p[((kt * 32 + nt) * 64 + l) * 8]);
                acc1[0][j] = __builtin_amdgcn_mfma_f32_16x16x32_bf16(af, xb0, acc1[0][j], 0, 0, 0);
                acc1[1][j] = __builtin_amdgcn_mfma_f32_16x16x32_bf16(af, xb1, acc1[1][j], 0, 0, 0);
            }
        }

        // tanh + pack hidden into LDS (row-major [batchrow][hiddendim])
#pragma unroll
        for (int mt = 0; mt < 2; ++mt)
#pragma unroll
            for (int j = 0; j < 4; ++j) {
                bf16x4 p;
#pragma unroll
                for (int i = 0; i < 4; ++i) p[i] = f2bf(tanh_fast(acc1[mt][j][i]));
                *reinterpret_cast<bf16x4*>(&H[(mt * 16 + l16) * HLD + (w * 4 + j) * 16 + lg * 4]) = p;
            }
        __syncthreads();

        // ---- GEMM2: f^T = W2^T (A) x hidden^T (B), K = 512
        f32x4 acc2[2][2];
#pragma unroll
        for (int mt = 0; mt < 2; ++mt)
#pragma unroll
            for (int j2 = 0; j2 < 2; ++j2)
                acc2[mt][j2] = (f32x4){b2v[j2], b2v[j2], b2v[j2], b2v[j2]};

#pragma unroll
        for (int kt = 0; kt < 16; ++kt) {
            bf16x8 hb0 = *reinterpret_cast<const bf16x8*>(&H[(0 * 16 + l16) * HLD + kt * 32 + lg * 8]);
            bf16x8 hb1 = *reinterpret_cast<const bf16x8*>(&H[(1 * 16 + l16) * HLD + kt * 32 + lg * 8]);
#pragma unroll
            for (int j2 = 0; j2 < 2; ++j2) {
                bf16x8 af = *reinterpret_cast<const bf16x8*>(&W2p[((kt * 16 + (w * 2 + j2)) * 64 + l) * 8]);
                acc2[0][j2] = __builtin_amdgcn_mfma_f32_16x16x32_bf16(af, hb0, acc2[0][j2], 0, 0, 0);
                acc2[1][j2] = __builtin_amdgcn_mfma_f32_16x16x32_bf16(af, hb1, acc2[1][j2], 0, 0, 0);
            }
        }

        // z += h * f ; write z back to X (bf16) for next step
#pragma unroll
        for (int mt = 0; mt < 2; ++mt)
#pragma unroll
            for (int j2 = 0; j2 < 2; ++j2)
#pragma unroll
                for (int i = 0; i < 4; ++i)
                    z[mt][j2][i] += hstep[mt] * acc2[mt][j2][i];

        if (t < NSTEPS - 1) {
#pragma unroll
            for (int mt = 0; mt < 2; ++mt)
#pragma unroll
                for (int j2 = 0; j2 < 2; ++j2) {
                    bf16x4 p;
#pragma unroll
                    for (int i = 0; i < 4; ++i) p[i] = f2bf(z[mt][j2][i]);
                    *reinterpret_cast<bf16x4*>(&X[(mt * 16 + l16) * XLD + (w * 2 + j2) * 16 + lg * 4]) = p;
                }
            __syncthreads();
        }
    }

    // final store (f32)
#pragma unroll
    for (int mt = 0; mt < 2; ++mt)
#pragma unroll
        for (int j2 = 0; j2 < 2; ++j2)
            *reinterpret_cast<f32x4*>(
                &out[(row0 + mt * 16 + l16) * LATENT + (w * 2 + j2) * 16 + lg * 4]) = z[mt][j2];
}

extern "C" void kernel_launch(void* const* d_in, const int* in_sizes, int n_in,
                              void* d_out, int out_size, void* d_ws, size_t ws_size,
                              hipStream_t stream) {
    const float* zt = (const float*)d_in[0];
    const float* dtp = (const float*)d_in[1];
    const float* ut = (const float*)d_in[2];
    const float* W1 = (const float*)d_in[3];
    const float* b1 = (const float*)d_in[4];
    const float* W2 = (const float*)d_in[5];
    const float* b2 = (const float*)d_in[6];

    prep_weights<<<136, 256, 0, stream>>>(W1, W2);
    ode_kernel<<<BROWS / BM, 512, 0, stream>>>(zt, dtp, ut, b1, b2, (float*)d_out);
}

// Round 7
// 177.634 us; speedup vs baseline: 1.0563x; 1.0563x over previous
//
#include <hip/hip_runtime.h>
#include <hip/hip_bf16.h>

#define NSTEPS 20
#define BROWS  8192
#define LATENT 256
#define UDIM   16
#define HIDDEN 512
#define BM     32      // rows per block
#define XLD    296     // LDS row stride (bf16) for X: 148 words ≡ 20 (mod 32) -> 2-way (free)
#define HLD    536     // LDS row stride (bf16) for H: 268 words ≡ 12 (mod 32) -> 2-way (free)
                       // (was 520 ≡ 4 mod 32 -> 8-way conflict, 1.0e7 conflict cycles measured)

// packed-weight footprint (shorts)
#define W1P_SHORTS (9 * 32 * 64 * 8)     // 147456
#define W2P_SHORTS (16 * 16 * 64 * 8)    // 131072

// Packed weights live in module-scope device memory: allocated at .so load
// time (no hipMalloc, no d_ws, no d_out aliasing, no cross-block sync needed).
// Re-packed from the immutable W1/W2 inputs on every kernel_launch call ->
// deterministic across graph replays.
__device__ __align__(16) short g_Wpack[W1P_SHORTS + W2P_SHORTS];

typedef __attribute__((ext_vector_type(8))) short bf16x8;
typedef __attribute__((ext_vector_type(4))) short bf16x4;
typedef __attribute__((ext_vector_type(4))) float f32x4;

__device__ __forceinline__ short f2bf(float x) {
    union { __hip_bfloat16 h; short s; } u;
    u.h = __float2bfloat16(x);
    return u.s;
}

__device__ __forceinline__ float tanh_fast(float x) {
    // tanh(x) = 1 - 2/(exp(2x)+1); robust at +-inf
    float e = __expf(2.0f * x);
    return 1.0f - 2.0f * __builtin_amdgcn_rcpf(e + 1.0f);
}

// Pack W1 (272x512, zero-padded K->288) and W2 (512x256) into per-fragment
// order: frag(kt,nt): lane l holds W[k = kt*32 + (l>>4)*8 + j][n = nt*16 + (l&15)],
// j=0..7, stored as 8 contiguous bf16 per lane (one 16B load per fragment).
__global__ void prep_weights(const float* __restrict__ W1, const float* __restrict__ W2) {
    short* W1p = g_Wpack;
    short* W2p = g_Wpack + W1P_SHORTS;
    int t = blockIdx.x * 256 + threadIdx.x;
    if (t < 9 * 32 * 64) {
        int l = t & 63, f = t >> 6;          // f: 0..287 = kt*32+nt
        int kt = f >> 5, nt = f & 31;
        int k0 = kt * 32 + ((l >> 4) << 3);
        int n = nt * 16 + (l & 15);
        bf16x8 o;
#pragma unroll
        for (int j = 0; j < 8; ++j) {
            int k = k0 + j;
            o[j] = (k < 272) ? f2bf(W1[k * 512 + n]) : (short)0;
        }
        *reinterpret_cast<bf16x8*>(W1p + t * 8) = o;
    } else if (t < 9 * 32 * 64 + 16 * 16 * 64) {
        int t2 = t - 9 * 32 * 64;
        int l = t2 & 63, f = t2 >> 6;        // f: 0..255 = kt*16+nt
        int kt = f >> 4, nt = f & 15;
        int k0 = kt * 32 + ((l >> 4) << 3);
        int n = nt * 16 + (l & 15);
        bf16x8 o;
#pragma unroll
        for (int j = 0; j < 8; ++j) o[j] = f2bf(W2[(k0 + j) * 256 + n]);
        *reinterpret_cast<bf16x8*>(W2p + t2 * 8) = o;
    }
}

// One block = 32 rows, 8 waves. Both GEMMs operand-swapped: D = W^T x X^T so
// the D fragment packs back into row-major [row][feature] LDS as contiguous
// b64 writes; activation B-fragments are contiguous b128 reads. z stays in
// f32 registers all 20 steps.
// NEW (r7): each wave caches its entire W2 slice (32 fragments = 128 VGPR) in
// registers across all 20 steps -> GEMM2 reads zero weight bytes from L2 per
// step; per-CU L2 weight stream drops 544KB -> 288KB per step.
__global__ __launch_bounds__(512, 2) void ode_kernel(
    const float* __restrict__ zt, const float* __restrict__ dtp,
    const float* __restrict__ ut, const float* __restrict__ b1,
    const float* __restrict__ b2, float* __restrict__ out) {
    __shared__ __align__(16) short X[BM * XLD];
    __shared__ __align__(16) short H[BM * HLD];

    const short* W1p = g_Wpack;
    const short* W2p = g_Wpack + W1P_SHORTS;

    const int tid = threadIdx.x;
    const int w = tid >> 6;          // wave 0..7
    const int l = tid & 63;
    const int l16 = l & 15;
    const int lg = l >> 4;           // 0..3
    const int row0 = blockIdx.x * BM;

    // biases for this wave's output tiles
    float b1v[4], b2v[2];
#pragma unroll
    for (int j = 0; j < 4; ++j) b1v[j] = b1[(w * 4 + j) * 16 + l16];
#pragma unroll
    for (int j = 0; j < 2; ++j) b2v[j] = b2[(w * 2 + j) * 16 + l16];

    // per-row step size h = dt/NSTEPS (one row per lane16 per mt)
    float hstep[2];
#pragma unroll
    for (int mt = 0; mt < 2; ++mt)
        hstep[mt] = dtp[row0 + mt * 16 + l16] * (1.0f / NSTEPS);

    // W2 slice for this wave, resident in VGPRs for all 20 steps.
    // frag index f = kt*2 + j2 (kt = 0..15, j2 = 0..1), all indices static.
    bf16x8 w2f[32];
#pragma unroll
    for (int kt = 0; kt < 16; ++kt)
#pragma unroll
        for (int j2 = 0; j2 < 2; ++j2)
            w2f[kt * 2 + j2] = *reinterpret_cast<const bf16x8*>(
                &W2p[((kt * 16 + (w * 2 + j2)) * 64 + l) * 8]);

    // z registers: z[mt][j2][i] = z[row0+mt*16+l16][(w*2+j2)*16 + lg*4 + i]
    f32x4 z[2][2];
#pragma unroll
    for (int mt = 0; mt < 2; ++mt)
#pragma unroll
        for (int j2 = 0; j2 < 2; ++j2)
            z[mt][j2] = *reinterpret_cast<const f32x4*>(
                &zt[(row0 + mt * 16 + l16) * LATENT + (w * 2 + j2) * 16 + lg * 4]);

    // init: ut columns (256..271) + zero pad (272..287) of X
    {
        int r = tid >> 4, c = tid & 15;   // 512 threads = 32 rows x 16 cols
        X[r * XLD + 256 + c] = f2bf(ut[(row0 + r) * UDIM + c]);
        X[r * XLD + 272 + c] = 0;
    }
    // init: z columns of X (bf16)
#pragma unroll
    for (int mt = 0; mt < 2; ++mt)
#pragma unroll
        for (int j2 = 0; j2 < 2; ++j2) {
            bf16x4 p;
#pragma unroll
            for (int i = 0; i < 4; ++i) p[i] = f2bf(z[mt][j2][i]);
            *reinterpret_cast<bf16x4*>(&X[(mt * 16 + l16) * XLD + (w * 2 + j2) * 16 + lg * 4]) = p;
        }
    __syncthreads();

#pragma unroll 1
    for (int t = 0; t < NSTEPS; ++t) {
        // ---- GEMM1: hidden^T = W1^T (A, streamed from L2) x X^T (B), K = 288
        f32x4 acc1[2][4];
#pragma unroll
        for (int mt = 0; mt < 2; ++mt)
#pragma unroll
            for (int j = 0; j < 4; ++j)
                acc1[mt][j] = (f32x4){b1v[j], b1v[j], b1v[j], b1v[j]};

#pragma unroll
        for (int kt = 0; kt < 9; ++kt) {
            bf16x8 xb0 = *reinterpret_cast<const bf16x8*>(&X[(0 * 16 + l16) * XLD + kt * 32 + lg * 8]);
            bf16x8 xb1 = *reinterpret_cast<const bf16x8*>(&X[(1 * 16 + l16) * XLD + kt * 32 + lg * 8]);
#pragma unroll
            for (int j = 0; j < 4; ++j) {
                int nt = w * 4 + j;
                bf16x8 af = *reinterpret_cast<const bf16x8*>(&W1p[((kt * 32 + nt) * 64 + l) * 8]);
                acc1[0][j] = __builtin_amdgcn_mfma_f32_16x16x32_bf16(af, xb0, acc1[0][j], 0, 0, 0);
                acc1[1][j] = __builtin_amdgcn_mfma_f32_16x16x32_bf16(af, xb1, acc1[1][j], 0, 0, 0);
            }
        }

        // tanh + pack hidden into LDS (row-major [batchrow][hiddendim])
#pragma unroll
        for (int mt = 0; mt < 2; ++mt)
#pragma unroll
            for (int j = 0; j < 4; ++j) {
                bf16x4 p;
#pragma unroll
                for (int i = 0; i < 4; ++i) p[i] = f2bf(tanh_fast(acc1[mt][j][i]));
                *reinterpret_cast<bf16x4*>(&H[(mt * 16 + l16) * HLD + (w * 4 + j) * 16 + lg * 4]) = p;
            }
        __syncthreads();

        // ---- GEMM2: f^T = W2^T (A, in registers) x hidden^T (B), K = 512
        f32x4 acc2[2][2];
#pragma unroll
        for (int mt = 0; mt < 2; ++mt)
#pragma unroll
            for (int j2 = 0; j2 < 2; ++j2)
                acc2[mt][j2] = (f32x4){b2v[j2], b2v[j2], b2v[j2], b2v[j2]};

#pragma unroll
        for (int kt = 0; kt < 16; ++kt) {
            bf16x8 hb0 = *reinterpret_cast<const bf16x8*>(&H[(0 * 16 + l16) * HLD + kt * 32 + lg * 8]);
            bf16x8 hb1 = *reinterpret_cast<const bf16x8*>(&H[(1 * 16 + l16) * HLD + kt * 32 + lg * 8]);
#pragma unroll
            for (int j2 = 0; j2 < 2; ++j2) {
                acc2[0][j2] = __builtin_amdgcn_mfma_f32_16x16x32_bf16(w2f[kt * 2 + j2], hb0, acc2[0][j2], 0, 0, 0);
                acc2[1][j2] = __builtin_amdgcn_mfma_f32_16x16x32_bf16(w2f[kt * 2 + j2], hb1, acc2[1][j2], 0, 0, 0);
            }
        }

        // z += h * f ; write z back to X (bf16) for next step
#pragma unroll
        for (int mt = 0; mt < 2; ++mt)
#pragma unroll
            for (int j2 = 0; j2 < 2; ++j2)
#pragma unroll
                for (int i = 0; i < 4; ++i)
                    z[mt][j2][i] += hstep[mt] * acc2[mt][j2][i];

        if (t < NSTEPS - 1) {
#pragma unroll
            for (int mt = 0; mt < 2; ++mt)
#pragma unroll
                for (int j2 = 0; j2 < 2; ++j2) {
                    bf16x4 p;
#pragma unroll
                    for (int i = 0; i < 4; ++i) p[i] = f2bf(z[mt][j2][i]);
                    *reinterpret_cast<bf16x4*>(&X[(mt * 16 + l16) * XLD + (w * 2 + j2) * 16 + lg * 4]) = p;
                }
            __syncthreads();
        }
    }

    // final store (f32)
#pragma unroll
    for (int mt = 0; mt < 2; ++mt)
#pragma unroll
        for (int j2 = 0; j2 < 2; ++j2)
            *reinterpret_cast<f32x4*>(
                &out[(row0 + mt * 16 + l16) * LATENT + (w * 2 + j2) * 16 + lg * 4]) = z[mt][j2];
}

extern "C" void kernel_launch(void* const* d_in, const int* in_sizes, int n_in,
                              void* d_out, int out_size, void* d_ws, size_t ws_size,
                              hipStream_t stream) {
    const float* zt = (const float*)d_in[0];
    const float* dtp = (const float*)d_in[1];
    const float* ut = (const float*)d_in[2];
    const float* W1 = (const float*)d_in[3];
    const float* b1 = (const float*)d_in[4];
    const float* W2 = (const float*)d_in[5];
    const float* b2 = (const float*)d_in[6];

    prep_weights<<<136, 256, 0, stream>>>(W1, W2);
    ode_kernel<<<BROWS / BM, 512, 0, stream>>>(zt, dtp, ut, b1, b2, (float*)d_out);
}